// Round 3
// baseline (91.704 us; speedup 1.0000x reference)
//
#include <hip/hip_runtime.h>
#include <hip/hip_fp16.h>

// TensorFusion: out = tanh(tanh(tanh(fusion@W1+b1)@W2+b2)@W3+b3)
// fusion[b,(i,j,k)] = a_h[b,i]*v_h[b,j]*t_h[b,k], a_h=[1,a], 65^3 = 274625 cols.
// K decomposes into 4291 segments of K=64 (+ row 0 folded into tail bias).
// Per segment: A[b,t] = scale[b]*inner[b,t] generated in-register (f16),
// W1 seg tile (64k x 64n fp32) reg-staged -> f16 -> LDS [n][k] XOR-swizzled.
// DEPTH-3 register pipeline: sets s,s+1,s+2 outstanding -> counted vmcnt waits,
// raw s_barrier (no vmcnt drain). Grid=256 (1 block/CU), 512 thr, BM=512.
// Split-K f16 partials [row][256][64] reduced in tail fused with the 64x64 MLP.

typedef _Float16 f16;
typedef f16 f16x8 __attribute__((ext_vector_type(8)));
typedef f16 f16x2 __attribute__((ext_vector_type(2)));
typedef float fx4 __attribute__((ext_vector_type(4)));

__device__ __forceinline__ void seg_decode(int s, int& ia, int& iv, int& isel,
                                           int& rowbase, int& rowstride) {
  if (s < 4096)      { int i = s >> 6, j = s & 63; ia = i; iv = j; isel = 0;
                       rowbase = (i+1)*4225 + (j+1)*65 + 1; rowstride = 1; }
  else if (s < 4160) { int i = s - 4096; ia = i; iv = -1; isel = 2;
                       rowbase = (i+1)*4225 + 65; rowstride = 65; }
  else if (s < 4224) { int i = s - 4160; ia = i; iv = -1; isel = 0;
                       rowbase = (i+1)*4225 + 1; rowstride = 1; }
  else if (s < 4288) { int j = s - 4224; ia = -1; iv = j; isel = 0;
                       rowbase = (j+1)*65 + 1; rowstride = 1; }
  else if (s == 4288){ ia = -1; iv = -1; isel = 1; rowbase = 4225; rowstride = 4225; }
  else if (s == 4289){ ia = -1; iv = -1; isel = 2; rowbase = 65;   rowstride = 65; }
  else if (s == 4290){ ia = -1; iv = -1; isel = 0; rowbase = 1;    rowstride = 1; }
  else               { ia = -2; iv = -1; isel = 0; rowbase = 1;    rowstride = 1; } // dummy: scale 0
}

__device__ __forceinline__ f16x8 cvt8(fx4 x0, fx4 x1) {
  f16x8 f;
  f[0]=(f16)x0[0]; f[1]=(f16)x0[1]; f[2]=(f16)x0[2]; f[3]=(f16)x0[3];
  f[4]=(f16)x1[0]; f[5]=(f16)x1[1]; f[6]=(f16)x1[2]; f[7]=(f16)x1[3];
  return f;
}
__device__ __forceinline__ f16x8 cvt8s(float a0,float a1,float a2,float a3,
                                       float a4,float a5,float a6,float a7){
  f16x8 f; f[0]=(f16)a0; f[1]=(f16)a1; f[2]=(f16)a2; f[3]=(f16)a3;
  f[4]=(f16)a4; f[5]=(f16)a5; f[6]=(f16)a6; f[7]=(f16)a7; return f;
}

// ---------------- stage 1: the big implicit GEMM ----------------
__global__ __launch_bounds__(512, 2) void fusion_gemm(
    const float* __restrict__ W1, const float* __restrict__ a,
    const float* __restrict__ v, const float* __restrict__ l,
    f16* __restrict__ partials)
{
  __shared__ f16 btile[2][4096];      // [n][k-chunk swizzled], 128 B/row
  __shared__ f16 pl[2][512];          // per-row scale

  const int tid  = threadIdx.x;
  const int bid  = blockIdx.x;
  const int lane = tid & 63;
  const int wave = tid >> 6;          // 0..7
  const int l15  = lane & 15;
  const int l4   = lane >> 4;         // 0..3
  const int n_st = tid & 63;          // staging: W1 col (== lane)
  const int kg   = wave;              // staging: k-octet (== wave)

  // A-fragments of l (f16) in registers: [mt][ks], rows wave*64+mt*16+l15
  f16x8 lfrag[4][2];
  #pragma unroll
  for (int mt = 0; mt < 4; ++mt) {
    int row = (wave << 6) + (mt << 4) + l15;
    #pragma unroll
    for (int ks = 0; ks < 2; ++ks) {
      const float* p = l + (row << 6) + (ks << 5) + (l4 << 3);
      lfrag[mt][ks] = cvt8(*(const fx4*)p, *(const fx4*)(p + 4));
    }
  }

  fx4 acc[4][4] = {};                 // 64 VGPRs: rows wave*64+mt*16, cols nt*16

  float wv[3][8];                     // depth-3 staging slots (all indices static)
  float spa[3], spv[3];
  const int segbase = bid * 17;       // 256*17 = 4352 >= 4291 (61 scale-0 dummies)

#define ISSUE(SL, SEG) do {                                                     \
    int s_ = (SEG); int ia_, iv_, isel_, rb_, rs_;                              \
    seg_decode(s_, ia_, iv_, isel_, rb_, rs_);                                  \
    const int rstep_ = rs_ << 6;                                                \
    const float* src_ = W1 + (size_t)(rb_ + (kg << 3) * rs_) * 64 + n_st;       \
    wv[SL][0] = src_[0];                  wv[SL][1] = src_[rstep_];             \
    wv[SL][2] = src_[rstep_ * 2];         wv[SL][3] = src_[rstep_ * 3];         \
    wv[SL][4] = src_[(size_t)rstep_ * 4]; wv[SL][5] = src_[(size_t)rstep_ * 5]; \
    wv[SL][6] = src_[(size_t)rstep_ * 6]; wv[SL][7] = src_[(size_t)rstep_ * 7]; \
    spa[SL] = (ia_ >= 0) ? a[(tid << 6) + ia_] : (ia_ == -1 ? 1.0f : 0.0f);     \
    spv[SL] = (iv_ >= 0) ? v[(tid << 6) + iv_] : 1.0f;                          \
  } while (0)

#define BODY(IDX, SL, BUF) do {                                                 \
    /* cvt slot SL (counted vmcnt: 2 younger sets stay in flight) -> LDS */     \
    f16x8 c_ = cvt8s(wv[SL][0], wv[SL][1], wv[SL][2], wv[SL][3],                \
                     wv[SL][4], wv[SL][5], wv[SL][6], wv[SL][7]);               \
    *(f16x8*)&btile[BUF][(n_st << 6) + (((kg << 1) ^ ((n_st & 7) << 1)) << 2)] = c_; \
    pl[BUF][tid] = (f16)(spa[SL] * spv[SL]);                                    \
    if ((IDX) + 3 < 17) ISSUE(SL, segbase + (IDX) + 3);                         \
    asm volatile("s_waitcnt lgkmcnt(0)\n\ts_barrier" ::: "memory");             \
    __builtin_amdgcn_sched_barrier(0);                                          \
    { int s_ = segbase + (IDX); int ia_, iv_, isel_, rb_, rs_;                  \
      seg_decode(s_, ia_, iv_, isel_, rb_, rs_);                                \
      const float* gsrc_ = (isel_ == 1) ? a : v;                                \
      _Pragma("unroll")                                                         \
      for (int ks = 0; ks < 2; ++ks) {                                          \
        f16x8 bf_[4];                                                           \
        _Pragma("unroll")                                                       \
        for (int nt = 0; nt < 4; ++nt) {                                        \
          int n_ = (nt << 4) + l15;                                             \
          int c0_ = (ks << 3) + (l4 << 1);                                      \
          bf_[nt] = *(const f16x8*)&btile[BUF][(n_ << 6) + ((c0_ ^ ((n_ & 7) << 1)) << 2)]; \
        }                                                                       \
        _Pragma("unroll")                                                       \
        for (int mt = 0; mt < 4; ++mt) {                                        \
          int row_ = (wave << 6) + (mt << 4) + l15;                             \
          f16 ps_ = pl[BUF][row_];                                              \
          f16x8 lv_;                                                            \
          if (isel_ == 0) lv_ = lfrag[mt][ks];                                  \
          else { const float* p_ = gsrc_ + (row_ << 6) + (ks << 5) + (l4 << 3); \
                 lv_ = cvt8(*(const fx4*)p_, *(const fx4*)(p_ + 4)); }          \
          f16x2 ps2_ = { ps_, ps_ };                                            \
          f16x8 av_;                                                            \
          ((f16x2*)&av_)[0] = ((f16x2*)&lv_)[0] * ps2_;                         \
          ((f16x2*)&av_)[1] = ((f16x2*)&lv_)[1] * ps2_;                         \
          ((f16x2*)&av_)[2] = ((f16x2*)&lv_)[2] * ps2_;                         \
          ((f16x2*)&av_)[3] = ((f16x2*)&lv_)[3] * ps2_;                         \
          _Pragma("unroll")                                                     \
          for (int nt = 0; nt < 4; ++nt)                                        \
            acc[mt][nt] = __builtin_amdgcn_mfma_f32_16x16x32_f16(av_, bf_[nt], acc[mt][nt], 0, 0, 0); \
        }                                                                       \
      }                                                                         \
    }                                                                           \
  } while (0)

  // prologue: fill the 3 slots
  ISSUE(0, segbase + 0);
  ISSUE(1, segbase + 1);
  ISSUE(2, segbase + 2);

  // 17 bodies; (SL,BUF) = (idx%3, idx&1), period 6
  #pragma unroll 1
  for (int t = 0; t < 2; ++t) {
    const int b6 = t * 6;
    BODY(b6 + 0, 0, 0); BODY(b6 + 1, 1, 1); BODY(b6 + 2, 2, 0);
    BODY(b6 + 3, 0, 1); BODY(b6 + 4, 1, 0); BODY(b6 + 5, 2, 1);
  }
  BODY(12, 0, 0); BODY(13, 1, 1); BODY(14, 2, 0);
  BODY(15, 0, 1); BODY(16, 1, 0);

#undef ISSUE
#undef BODY

  // epilogue: f16 partials, layout [row][p=bid][n] (tail reads contiguous)
  #pragma unroll
  for (int mt = 0; mt < 4; ++mt)
    #pragma unroll
    for (int nt = 0; nt < 4; ++nt)
      #pragma unroll
      for (int r = 0; r < 4; ++r) {
        int row = (wave << 6) + (mt << 4) + (l4 << 2) + r;
        int col = (nt << 4) + l15;
        partials[((size_t)row << 14) + (bid << 6) + col] = (f16)acc[mt][nt][r];
      }
}

// ---------------- tail: reduce partials + bias + tanh + 2x 64x64 GEMM ----------------
__global__ __launch_bounds__(256) void tail_kernel(
    const f16* __restrict__ partials, const float* __restrict__ W1, const float* __restrict__ b1,
    const float* __restrict__ W2, const float* __restrict__ b2,
    const float* __restrict__ W3, const float* __restrict__ b3, float* __restrict__ out)
{
  __shared__ float red[256][8];
  __shared__ float hbuf[64];
  __shared__ float h2buf[64];
  const int row = blockIdx.x;          // 0..511
  const int t = threadIdx.x;
  const f16* base = partials + ((size_t)row << 14);  // 16384 f16, contiguous

  float s[8] = {0.f,0.f,0.f,0.f,0.f,0.f,0.f,0.f};
  #pragma unroll
  for (int j = 0; j < 8; ++j) {
    f16x8 vv = *(const f16x8*)(base + (((j << 8) + t) << 3));
    #pragma unroll
    for (int e = 0; e < 8; ++e) s[e] += (float)vv[e];
  }
  #pragma unroll
  for (int e = 0; e < 8; ++e) red[t][e] = s[e];
  __syncthreads();
  if (t < 64) {
    float acc = b1[t] + W1[t];         // + row-0 (1*1*1) term
    #pragma unroll
    for (int k = 0; k < 32; ++k) acc += red[(t >> 3) + (k << 3)][t & 7];
    hbuf[t] = tanhf(acc);
  }
  __syncthreads();
  if (t < 64) {
    float acc = b2[t];
    #pragma unroll 8
    for (int k = 0; k < 64; ++k) acc += hbuf[k] * W2[(k << 6) + t];
    h2buf[t] = tanhf(acc);
  }
  __syncthreads();
  if (t < 64) {
    float acc = b3[t];
    #pragma unroll 8
    for (int k = 0; k < 64; ++k) acc += h2buf[k] * W3[(k << 6) + t];
    out[(row << 6) + t] = tanhf(acc);
  }
}

extern "C" void kernel_launch(void* const* d_in, const int* in_sizes, int n_in,
                              void* d_out, int out_size, void* d_ws, size_t ws_size,
                              hipStream_t stream) {
  const float* l  = (const float*)d_in[0];
  const float* a  = (const float*)d_in[1];
  const float* v  = (const float*)d_in[2];
  const float* W1 = (const float*)d_in[3];
  const float* b1 = (const float*)d_in[4];
  const float* W2 = (const float*)d_in[5];
  const float* b2 = (const float*)d_in[6];
  const float* W3 = (const float*)d_in[7];
  const float* b3 = (const float*)d_in[8];
  float* out = (float*)d_out;

  f16* partials = (f16*)d_ws;          // 16 MB

  hipLaunchKernelGGL(fusion_gemm, dim3(256), dim3(512), 0, stream,
                     W1, a, v, l, partials);
  hipLaunchKernelGGL(tail_kernel, dim3(512), dim3(256), 0, stream,
                     partials, W1, b1, W2, b2, W3, b3, out);
}

// Round 4
// 61.831 us; speedup vs baseline: 1.4831x; 1.4831x over previous
//
#include <hip/hip_runtime.h>
#include <hip/hip_fp16.h>

// TensorFusion: out = tanh(tanh(tanh(fusion@W1+b1)@W2+b2)@W3+b3)
// fusion[b,(i,j,k)] = a_h[b,i]*v_h[b,j]*t_h[b,k], a_h=[1,a], 65^3 = 274625 cols.
// K decomposes into 4291 segments of K=64 (+ row 0 folded into tail bias).
// Per segment: A[b,t] = scale[b]*inner[b,t] generated in-register (f16).
// W1 seg tile (64k x 64n fp32) staged via global_load_lds (16B, coalesced)
// into LDS [k][n] fp32 with chunk-rotation swizzle applied on the GLOBAL
// source side (G21); B-frags read as 8x b32 (2 lanes/bank = free), cvt f16
// at read. Depth-4 pipeline: explicit literal s_waitcnt vmcnt(8), raw
// s_barrier, 6-buffer rotation. Grid=256 (1 block/CU), 512 thr, BM=512
// -> W1 read exactly once. Split-K f16 partials [row][256][64] reduced in
// tail kernel fused with the 64x64 MLP.

typedef _Float16 f16;
typedef f16 f16x8 __attribute__((ext_vector_type(8)));
typedef f16 f16x2 __attribute__((ext_vector_type(2)));
typedef float fx4 __attribute__((ext_vector_type(4)));
typedef unsigned int u32;

#define WS_AT    0
#define WS_VT    131072
#define WS_PART  262144   // f16 [512][256][64] = 16777216 B

__device__ __forceinline__ void load_lds16(const float* g, float* lds) {
  __builtin_amdgcn_global_load_lds((const __attribute__((address_space(1))) u32*)g,
                                   (__attribute__((address_space(3))) u32*)lds, 16, 0, 0);
}

__device__ __forceinline__ void seg_decode(int s, int& ia, int& iv, int& isel,
                                           int& rowbase, int& rowstride) {
  if (s < 4096)      { int i = s >> 6, j = s & 63; ia = i; iv = j; isel = 0;
                       rowbase = (i+1)*4225 + (j+1)*65 + 1; rowstride = 1; }
  else if (s < 4160) { int i = s - 4096; ia = i; iv = -1; isel = 2;
                       rowbase = (i+1)*4225 + 65; rowstride = 65; }
  else if (s < 4224) { int i = s - 4160; ia = i; iv = -1; isel = 0;
                       rowbase = (i+1)*4225 + 1; rowstride = 1; }
  else if (s < 4288) { int j = s - 4224; ia = -1; iv = j; isel = 0;
                       rowbase = (j+1)*65 + 1; rowstride = 1; }
  else if (s == 4288){ ia = -1; iv = -1; isel = 1; rowbase = 4225; rowstride = 4225; }
  else if (s == 4289){ ia = -1; iv = -1; isel = 2; rowbase = 65;   rowstride = 65; }
  else if (s == 4290){ ia = -1; iv = -1; isel = 0; rowbase = 1;    rowstride = 1; }
  else               { ia = -2; iv = -1; isel = 0; rowbase = 1;    rowstride = 1; } // dummy: scale 0
}

__device__ __forceinline__ f16x8 cvt8(fx4 x0, fx4 x1) {
  f16x8 f;
  f[0]=(f16)x0[0]; f[1]=(f16)x0[1]; f[2]=(f16)x0[2]; f[3]=(f16)x0[3];
  f[4]=(f16)x1[0]; f[5]=(f16)x1[1]; f[6]=(f16)x1[2]; f[7]=(f16)x1[3];
  return f;
}
__device__ __forceinline__ f16x8 cvt8s(float a0,float a1,float a2,float a3,
                                       float a4,float a5,float a6,float a7){
  f16x8 f; f[0]=(f16)a0; f[1]=(f16)a1; f[2]=(f16)a2; f[3]=(f16)a3;
  f[4]=(f16)a4; f[5]=(f16)a5; f[6]=(f16)a6; f[7]=(f16)a7; return f;
}

// ---------------- prep: aT/vT transposes (coalesced scale loads) ----------------
__global__ __launch_bounds__(256) void prep_kernel(
    const float* __restrict__ a, const float* __restrict__ v,
    float* __restrict__ aT, float* __restrict__ vT)
{
  int g = blockIdx.x * 256 + threadIdx.x;   // 2*32768 items
  int which = g >> 15;
  int idx = g & 32767;
  if (which == 0) aT[idx] = a[((idx & 511) << 6) + (idx >> 9)];  // aT[c][r]=a[r][c]
  else            vT[idx] = v[((idx & 511) << 6) + (idx >> 9)];
}

// ---------------- stage 1: the big implicit GEMM ----------------
__global__ __launch_bounds__(512, 2) void fusion_gemm(
    const float* __restrict__ W1,
    const float* __restrict__ aT, const float* __restrict__ vT,
    const float* __restrict__ a, const float* __restrict__ v, const float* __restrict__ l,
    f16* __restrict__ partials)
{
  __shared__ float sbuf[6][4096];     // 6 seg-buffers, [k][n] fp32, chunk-swizzled
  __shared__ f16 pl_all[17][512];     // per-seg per-row scales

  const int tid  = threadIdx.x;
  const int bid  = blockIdx.x;
  const int lane = tid & 63;
  const int wave = tid >> 6;          // 0..7
  const int l15  = lane & 15;
  const int l4   = lane >> 4;         // 0..3
  const int segbase = bid * 17;       // 256*17 = 4352 >= 4291

  // ---- scales (once): pl_all[t][row], coalesced via aT/vT ----
  #pragma unroll 1
  for (int t = 0; t < 17; ++t) {
    int s = segbase + t, ia, iv, is_, rb, rs;
    seg_decode(s, ia, iv, is_, rb, rs);
    float spa = (ia >= 0) ? aT[(ia << 9) + tid] : (ia == -1 ? 1.0f : 0.0f);
    float spv = (iv >= 0) ? vT[(iv << 9) + tid] : 1.0f;
    pl_all[t][tid] = (f16)(spa * spv);
  }

  // ---- A-operand preloads (f16 regs): lfrag (inner=l), vfrag (inner=v) ----
  f16x8 lfrag[4][2], vfrag[4][2];
  #pragma unroll
  for (int mt = 0; mt < 4; ++mt) {
    int row = (wave << 6) + (mt << 4) + l15;
    #pragma unroll
    for (int ks = 0; ks < 2; ++ks) {
      const float* pl_ = l + (row << 6) + (ks << 5) + (l4 << 3);
      lfrag[mt][ks] = cvt8(*(const fx4*)pl_, *(const fx4*)(pl_ + 4));
      const float* pv_ = v + (row << 6) + (ks << 5) + (l4 << 3);
      vfrag[mt][ks] = cvt8(*(const fx4*)pv_, *(const fx4*)(pv_ + 4));
    }
  }

  fx4 acc[4][4] = {};                 // 64 VGPRs

  // staging: 1024 chunks of 16B; chunk c -> k=c>>4, slot col c&15,
  // content col n4 = ((c&15) - 2*(k>>3)) & 15  (inverse of read rotation)
  const int c0 = (wave << 6) + lane;

#define STAGE(T, BUF) do {                                                   \
    int s_ = segbase + (T), ia_, iv_, is_, rb_, rs_;                         \
    seg_decode(s_, ia_, iv_, is_, rb_, rs_);                                 \
    _Pragma("unroll")                                                        \
    for (int h_ = 0; h_ < 2; ++h_) {                                         \
      int c_  = c0 + (h_ << 9);                                              \
      int k_  = c_ >> 4;                                                     \
      int n4_ = ((c_ & 15) - 2 * (k_ >> 3)) & 15;                            \
      const float* g_ = W1 + (size_t)(rb_ + k_ * rs_) * 64 + (n4_ << 2);     \
      load_lds16(g_, &sbuf[BUF][((wave << 6) + (h_ << 9)) << 2]);            \
    }                                                                        \
  } while (0)

  // prologue: 4 segments in flight
  STAGE(0, 0); STAGE(1, 1); STAGE(2, 2); STAGE(3, 3);

  int cur = 0, stg = 4;
  #pragma unroll 1
  for (int t = 0; t < 17; ++t) {
    if (t + 4 < 17) {
      STAGE(t + 4, stg);
      // counted wait: segs t+1..t+4 (8 loads) stay in flight; seg t is done
      asm volatile("s_waitcnt vmcnt(8) lgkmcnt(0)\n\ts_barrier" ::: "memory");
    } else {
      asm volatile("s_waitcnt vmcnt(0) lgkmcnt(0)\n\ts_barrier" ::: "memory");
    }
    __builtin_amdgcn_sched_barrier(0);

    int s = segbase + t;
    int isel = ((s >= 4096 && s < 4160) || s == 4289) ? 2 : (s == 4288 ? 1 : 0);
    const float* bufc = sbuf[cur];

    #pragma unroll
    for (int ks = 0; ks < 2; ++ks) {
      f16x8 bf[4];
      #pragma unroll
      for (int nt = 0; nt < 4; ++nt) {
        int n = (nt << 4) + l15;
        int col4 = ((n >> 2) + 2 * ((ks << 2) + l4)) & 15;     // rotation by k>>3
        int dw = (((ks << 5) + (l4 << 3)) << 6) + (col4 << 2) + (n & 3);
        bf[nt] = cvt8s(bufc[dw],       bufc[dw + 64],  bufc[dw + 128], bufc[dw + 192],
                       bufc[dw + 256], bufc[dw + 320], bufc[dw + 384], bufc[dw + 448]);
      }
      #pragma unroll
      for (int mt = 0; mt < 4; ++mt) {
        int row = (wave << 6) + (mt << 4) + l15;
        f16 ps = pl_all[t][row];
        f16x8 lv;
        if (isel == 0)      lv = lfrag[mt][ks];
        else if (isel == 2) lv = vfrag[mt][ks];
        else { const float* p_ = a + (row << 6) + (ks << 5) + (l4 << 3);
               lv = cvt8(*(const fx4*)p_, *(const fx4*)(p_ + 4)); }
        f16x2 ps2 = { ps, ps };
        f16x8 av;
        ((f16x2*)&av)[0] = ((f16x2*)&lv)[0] * ps2;
        ((f16x2*)&av)[1] = ((f16x2*)&lv)[1] * ps2;
        ((f16x2*)&av)[2] = ((f16x2*)&lv)[2] * ps2;
        ((f16x2*)&av)[3] = ((f16x2*)&lv)[3] * ps2;
        #pragma unroll
        for (int nt = 0; nt < 4; ++nt)
          acc[mt][nt] = __builtin_amdgcn_mfma_f32_16x16x32_f16(av, bf[nt], acc[mt][nt], 0, 0, 0);
      }
    }
    cur = (cur == 5) ? 0 : cur + 1;
    stg = (stg == 5) ? 0 : stg + 1;
  }
#undef STAGE

  // epilogue: f16 partials, layout [row][p=bid][n] (tail reads contiguous)
  #pragma unroll
  for (int mt = 0; mt < 4; ++mt)
    #pragma unroll
    for (int nt = 0; nt < 4; ++nt)
      #pragma unroll
      for (int r = 0; r < 4; ++r) {
        int row = (wave << 6) + (mt << 4) + (l4 << 2) + r;
        int col = (nt << 4) + l15;
        partials[((size_t)row << 14) + (bid << 6) + col] = (f16)acc[mt][nt][r];
      }
}

// ---------------- tail: reduce partials + bias + tanh + 2x 64x64 GEMM ----------------
__global__ __launch_bounds__(256) void tail_kernel(
    const f16* __restrict__ partials, const float* __restrict__ W1, const float* __restrict__ b1,
    const float* __restrict__ W2, const float* __restrict__ b2,
    const float* __restrict__ W3, const float* __restrict__ b3, float* __restrict__ out)
{
  __shared__ float red[256][8];
  __shared__ float hbuf[64];
  __shared__ float h2buf[64];
  const int row = blockIdx.x;          // 0..511
  const int t = threadIdx.x;
  const f16* base = partials + ((size_t)row << 14);  // 16384 f16, contiguous

  float s[8] = {0.f,0.f,0.f,0.f,0.f,0.f,0.f,0.f};
  #pragma unroll
  for (int j = 0; j < 8; ++j) {
    f16x8 vv = *(const f16x8*)(base + (((j << 8) + t) << 3));
    #pragma unroll
    for (int e = 0; e < 8; ++e) s[e] += (float)vv[e];
  }
  #pragma unroll
  for (int e = 0; e < 8; ++e) red[t][e] = s[e];
  __syncthreads();
  if (t < 64) {
    float acc = b1[t] + W1[t];         // + row-0 (1*1*1) term
    #pragma unroll
    for (int k = 0; k < 32; ++k) acc += red[(t >> 3) + (k << 3)][t & 7];
    hbuf[t] = tanhf(acc);
  }
  __syncthreads();
  if (t < 64) {
    float acc = b2[t];
    #pragma unroll 8
    for (int k = 0; k < 64; ++k) acc += hbuf[k] * W2[(k << 6) + t];
    h2buf[t] = tanhf(acc);
  }
  __syncthreads();
  if (t < 64) {
    float acc = b3[t];
    #pragma unroll 8
    for (int k = 0; k < 64; ++k) acc += h2buf[k] * W3[(k << 6) + t];
    out[(row << 6) + t] = tanhf(acc);
  }
}

extern "C" void kernel_launch(void* const* d_in, const int* in_sizes, int n_in,
                              void* d_out, int out_size, void* d_ws, size_t ws_size,
                              hipStream_t stream) {
  const float* l  = (const float*)d_in[0];
  const float* a  = (const float*)d_in[1];
  const float* v  = (const float*)d_in[2];
  const float* W1 = (const float*)d_in[3];
  const float* b1 = (const float*)d_in[4];
  const float* W2 = (const float*)d_in[5];
  const float* b2 = (const float*)d_in[6];
  const float* W3 = (const float*)d_in[7];
  const float* b3 = (const float*)d_in[8];
  float* out = (float*)d_out;

  char* ws = (char*)d_ws;
  float* aT = (float*)(ws + WS_AT);
  float* vT = (float*)(ws + WS_VT);
  f16* partials = (f16*)(ws + WS_PART);

  hipLaunchKernelGGL(prep_kernel, dim3(256), dim3(256), 0, stream, a, v, aT, vT);
  hipLaunchKernelGGL(fusion_gemm, dim3(256), dim3(512), 0, stream,
                     W1, aT, vT, a, v, l, partials);
  hipLaunchKernelGGL(tail_kernel, dim3(512), dim3(256), 0, stream,
                     partials, W1, b1, W2, b2, W3, b3, out);
}